// Round 2
// baseline (1311.445 us; speedup 1.0000x reference)
//
#include <hip/hip_runtime.h>

typedef unsigned short ushort_t;
typedef __attribute__((ext_vector_type(8))) short short8;
typedef __attribute__((ext_vector_type(4))) float f32x4;

#define LN_EPS 1e-5f

// LDS layout (bytes). f32 for residual/LN/output, bf16 for MFMA operand tiles.
// All row strides 16B-aligned.
#define XW_OFF   0                     // xw   f32  [64][132] = 33792   (live whole kernel)
#define XN_OFF   33792                 // xn   bf16 [64][136] = 17408
#define QKP_OFF  51200                 // q bf16 [4][64][40]=20480 ; k at +20480 ; p [4][64][72] alias ; y [64][136] alias
#define KK_OFF   (QKP_OFF + 20480)     // 71680
#define VT_OFF   92160                 // vT bf16 [4][32][72] = 18432
#define O_OFF    110592                // o  bf16 [64][136] = 17408  (ends 128000)
#define OUTT_OFF 92160                 // outT f32 [128][68] = 34816 alias over vT+o (dead in phase 6)
#define SMEM_BYTES 128000

static __device__ __forceinline__ ushort_t f2bf(float f) {
    union { float f; unsigned int u; } cv; cv.f = f;
    unsigned int x = cv.u + 0x7FFFu + ((cv.u >> 16) & 1u);   // RNE
    return (ushort_t)(x >> 16);
}

static __device__ __forceinline__ short8 loadw8(const float* p) {  // 8 f32 -> 8 bf16
    float4 a = *(const float4*)p;
    float4 b = *(const float4*)(p + 4);
    short8 r;
    r[0] = (short)f2bf(a.x); r[1] = (short)f2bf(a.y); r[2] = (short)f2bf(a.z); r[3] = (short)f2bf(a.w);
    r[4] = (short)f2bf(b.x); r[5] = (short)f2bf(b.y); r[6] = (short)f2bf(b.z); r[7] = (short)f2bf(b.w);
    return r;
}

__global__ __launch_bounds__(512) void wattn_kernel(
    const float* __restrict__ x,
    const float* __restrict__ ln_g,
    const float* __restrict__ ln_b,
    const float* __restrict__ w_qkv,   // [384][128] row-major (o,c)
    const float* __restrict__ b_qkv,
    const float* __restrict__ w_out,   // [128][128]
    const float* __restrict__ b_out,
    const float* __restrict__ w_cv,    // [128][128]
    const float* __restrict__ b_cv,
    float* __restrict__ out)
{
    extern __shared__ char smem[];
    float*    xw   = (float*)(smem + XW_OFF);      // [64][132]
    ushort_t* xn   = (ushort_t*)(smem + XN_OFF);   // [64][136]
    ushort_t* qls  = (ushort_t*)(smem + QKP_OFF);  // [4][64][40]
    ushort_t* kls  = (ushort_t*)(smem + KK_OFF);   // [4][64][40]
    ushort_t* pls  = (ushort_t*)(smem + QKP_OFF);  // [4][64][72] alias (q/k dead)
    ushort_t* yls  = (ushort_t*)(smem + QKP_OFF);  // [64][136]   alias (p dead)
    ushort_t* vls  = (ushort_t*)(smem + VT_OFF);   // [4][32][72]
    ushort_t* ols  = (ushort_t*)(smem + O_OFF);    // [64][136]
    float*    outT = (float*)(smem + OUTT_OFF);    // [128][68]   alias (vT,o dead)

    const int tid  = threadIdx.x;
    const int lane = tid & 63;
    const int wv   = tid >> 6;
    const int l15  = lane & 15;
    const int quad = lane >> 4;

    const int win = blockIdx.x;      // [B=2][nD=16][nH=16][nW=16]
    const int bN  = win >> 12;
    const int dz  = (win >> 8) & 15;
    const int hy  = (win >> 4) & 15;
    const int wx  = win & 15;
    const long base = ((long)(bN * 128) * 64 + dz * 4) * 4096 + (long)(hy * 4) * 64 + wx * 4;

    // ---------- Phase 0: gather window -> xw[t][c]  (float4 along W) ----------
    #pragma unroll
    for (int j = 0; j < 4; ++j) {
        int i  = tid + j * 512;      // [c:128][td:4][th:4]
        int c  = i >> 4;
        int td = (i >> 2) & 3;
        int th = i & 3;
        float4 v = *(const float4*)(x + base + (long)c * 262144 + td * 4096 + th * 64);
        int t0 = td * 16 + th * 4;
        xw[(t0 + 0) * 132 + c] = v.x;
        xw[(t0 + 1) * 132 + c] = v.y;
        xw[(t0 + 2) * 132 + c] = v.z;
        xw[(t0 + 3) * 132 + c] = v.w;
    }
    __syncthreads();

    // ---------- Phase 1: LayerNorm over channels -> xn (bf16) ----------
    {
        int t = tid >> 3;            // token, 8 threads/token
        int p = tid & 7;
        const float4* xp = (const float4*)(xw + t * 132 + p * 16);
        float4 v0 = xp[0], v1 = xp[1], v2 = xp[2], v3 = xp[3];
        float vals[16] = {v0.x,v0.y,v0.z,v0.w, v1.x,v1.y,v1.z,v1.w,
                          v2.x,v2.y,v2.z,v2.w, v3.x,v3.y,v3.z,v3.w};
        float s = 0.f, ss = 0.f;
        #pragma unroll
        for (int j = 0; j < 16; ++j) { s += vals[j]; ss += vals[j] * vals[j]; }
        #pragma unroll
        for (int off = 1; off < 8; off <<= 1) {
            s  += __shfl_xor(s, off, 64);
            ss += __shfl_xor(ss, off, 64);
        }
        float mu   = s * 0.0078125f;
        float var  = ss * 0.0078125f - mu * mu;
        float rstd = rsqrtf(var + LN_EPS);
        #pragma unroll
        for (int j = 0; j < 16; ++j) {
            int c = p * 16 + j;
            xn[t * 136 + c] = f2bf((vals[j] - mu) * rstd * ln_g[c] + ln_b[c]);
        }
    }
    __syncthreads();

    // ---------- Phase 2: QKV GEMM [64x128]@[128x384], wave owns 48 cols ----------
    {
        const int n_base = wv * 48;
        f32x4 acc[4][3];
        #pragma unroll
        for (int mi = 0; mi < 4; ++mi)
            #pragma unroll
            for (int ni = 0; ni < 3; ++ni) acc[mi][ni] = (f32x4){0.f, 0.f, 0.f, 0.f};
        #pragma unroll
        for (int ks = 0; ks < 4; ++ks) {
            int k0 = ks * 32 + quad * 8;
            short8 a[4], bfr[3];
            #pragma unroll
            for (int mi = 0; mi < 4; ++mi) a[mi] = *(const short8*)(xn + (mi * 16 + l15) * 136 + k0);
            #pragma unroll
            for (int ni = 0; ni < 3; ++ni) bfr[ni] = loadw8(w_qkv + (n_base + ni * 16 + l15) * 128 + k0);
            #pragma unroll
            for (int ni = 0; ni < 3; ++ni)
                #pragma unroll
                for (int mi = 0; mi < 4; ++mi)
                    acc[mi][ni] = __builtin_amdgcn_mfma_f32_16x16x32_bf16(a[mi], bfr[ni], acc[mi][ni], 0, 0, 0);
        }
        // epilogue: +bias, scatter q[h][t][d], k[h][t][d], vT[h][d][t]
        #pragma unroll
        for (int ni = 0; ni < 3; ++ni) {
            int col  = n_base + ni * 16 + l15;
            float bias = b_qkv[col];
            int sect = col >> 7;          // uniform per tile (16 | 128)
            int cc   = col & 127;
            int h = cc >> 5, d = cc & 31;
            #pragma unroll
            for (int mi = 0; mi < 4; ++mi)
                #pragma unroll
                for (int r = 0; r < 4; ++r) {
                    int row = mi * 16 + quad * 4 + r;
                    ushort_t val = f2bf(acc[mi][ni][r] + bias);
                    if (sect == 0)      qls[h * 2560 + row * 40 + d] = val;
                    else if (sect == 1) kls[h * 2560 + row * 40 + d] = val;
                    else                vls[h * 2304 + d * 72 + row] = val;
                }
        }
    }
    __syncthreads();

    // ---------- Phase 3/4: attention. wave w: head w>>1, q-rows (w&1)*32.. ----------
    {
        const int h  = wv >> 1;
        const int m0 = (wv & 1) * 32;
        const ushort_t* qh = qls + h * 2560;
        const ushort_t* kh = kls + h * 2560;
        f32x4 sc[2][4];
        #pragma unroll
        for (int mi = 0; mi < 2; ++mi)
            #pragma unroll
            for (int ni = 0; ni < 4; ++ni) sc[mi][ni] = (f32x4){0.f, 0.f, 0.f, 0.f};
        {
            int kq = quad * 8;           // K = 32: one MFMA k-step
            short8 a[2], bfr[4];
            #pragma unroll
            for (int mi = 0; mi < 2; ++mi) a[mi] = *(const short8*)(qh + (m0 + mi * 16 + l15) * 40 + kq);
            #pragma unroll
            for (int ni = 0; ni < 4; ++ni) bfr[ni] = *(const short8*)(kh + (ni * 16 + l15) * 40 + kq);
            #pragma unroll
            for (int ni = 0; ni < 4; ++ni)
                #pragma unroll
                for (int mi = 0; mi < 2; ++mi)
                    sc[mi][ni] = __builtin_amdgcn_mfma_f32_16x16x32_bf16(a[mi], bfr[ni], sc[mi][ni], 0, 0, 0);
        }
        const float scale = 0.1767766952966369f;   // 1/sqrt(32)
        float pv[2][4][4];
        #pragma unroll
        for (int mi = 0; mi < 2; ++mi)
            #pragma unroll
            for (int r = 0; r < 4; ++r) {
                float v0 = sc[mi][0][r] * scale, v1 = sc[mi][1][r] * scale;
                float v2 = sc[mi][2][r] * scale, v3 = sc[mi][3][r] * scale;
                float mx = fmaxf(fmaxf(v0, v1), fmaxf(v2, v3));
                #pragma unroll
                for (int off = 1; off < 16; off <<= 1) mx = fmaxf(mx, __shfl_xor(mx, off, 64));
                float e0 = __expf(v0 - mx), e1 = __expf(v1 - mx), e2 = __expf(v2 - mx), e3 = __expf(v3 - mx);
                float sum = e0 + e1 + e2 + e3;
                #pragma unroll
                for (int off = 1; off < 16; off <<= 1) sum += __shfl_xor(sum, off, 64);
                float inv = 1.f / sum;
                pv[mi][0][r] = e0 * inv; pv[mi][1][r] = e1 * inv;
                pv[mi][2][r] = e2 * inv; pv[mi][3][r] = e3 * inv;
            }
        __syncthreads();   // all waves done with q/k -> safe to overlay p
        ushort_t* ph = pls + h * 4608;
        #pragma unroll
        for (int mi = 0; mi < 2; ++mi)
            #pragma unroll
            for (int ni = 0; ni < 4; ++ni)
                #pragma unroll
                for (int r = 0; r < 4; ++r)
                    ph[(m0 + mi * 16 + quad * 4 + r) * 72 + ni * 16 + l15] = f2bf(pv[mi][ni][r]);
        __syncthreads();   // fence: p stores (ushort) vs short8 reloads below
        // P @ V   [32x64]@[64x32]
        f32x4 oacc[2][2];
        #pragma unroll
        for (int mi = 0; mi < 2; ++mi)
            #pragma unroll
            for (int ni = 0; ni < 2; ++ni) oacc[mi][ni] = (f32x4){0.f, 0.f, 0.f, 0.f};
        #pragma unroll
        for (int kk = 0; kk < 2; ++kk) {
            int kq = kk * 32 + quad * 8;
            short8 a[2], bfr[2];
            #pragma unroll
            for (int mi = 0; mi < 2; ++mi) a[mi] = *(const short8*)(ph + (m0 + mi * 16 + l15) * 72 + kq);
            #pragma unroll
            for (int ni = 0; ni < 2; ++ni) bfr[ni] = *(const short8*)(vls + h * 2304 + (ni * 16 + l15) * 72 + kq);
            #pragma unroll
            for (int ni = 0; ni < 2; ++ni)
                #pragma unroll
                for (int mi = 0; mi < 2; ++mi)
                    oacc[mi][ni] = __builtin_amdgcn_mfma_f32_16x16x32_bf16(a[mi], bfr[ni], oacc[mi][ni], 0, 0, 0);
        }
        #pragma unroll
        for (int mi = 0; mi < 2; ++mi)
            #pragma unroll
            for (int ni = 0; ni < 2; ++ni)
                #pragma unroll
                for (int r = 0; r < 4; ++r)
                    ols[(m0 + mi * 16 + quad * 4 + r) * 136 + h * 32 + ni * 16 + l15] = f2bf(oacc[mi][ni][r]);
    }
    __syncthreads();

    // ---------- Phase 5: out_proj [64x128]@[128x128] + attn residual -> y (bf16) ----------
    {
        const int n0 = wv * 16;
        f32x4 acc[4];
        #pragma unroll
        for (int mi = 0; mi < 4; ++mi) acc[mi] = (f32x4){0.f, 0.f, 0.f, 0.f};
        #pragma unroll
        for (int ks = 0; ks < 4; ++ks) {
            int k0 = ks * 32 + quad * 8;
            short8 bfr = loadw8(w_out + (n0 + l15) * 128 + k0);
            #pragma unroll
            for (int mi = 0; mi < 4; ++mi) {
                short8 a = *(const short8*)(ols + (mi * 16 + l15) * 136 + k0);
                acc[mi] = __builtin_amdgcn_mfma_f32_16x16x32_bf16(a, bfr, acc[mi], 0, 0, 0);
            }
        }
        int col = n0 + l15;
        float bias = b_out[col];
        #pragma unroll
        for (int mi = 0; mi < 4; ++mi)
            #pragma unroll
            for (int r = 0; r < 4; ++r) {
                int row = mi * 16 + quad * 4 + r;
                yls[row * 136 + col] = f2bf(acc[mi][r] + bias + xw[row * 132 + col]);
            }
    }
    __syncthreads();

    // ---------- Phase 6: conv [64x128]@[128x128] + input residual -> outT f32 [c][t] ----------
    {
        const int n0 = wv * 16;
        f32x4 acc[4];
        #pragma unroll
        for (int mi = 0; mi < 4; ++mi) acc[mi] = (f32x4){0.f, 0.f, 0.f, 0.f};
        #pragma unroll
        for (int ks = 0; ks < 4; ++ks) {
            int k0 = ks * 32 + quad * 8;
            short8 bfr = loadw8(w_cv + (n0 + l15) * 128 + k0);
            #pragma unroll
            for (int mi = 0; mi < 4; ++mi) {
                short8 a = *(const short8*)(yls + (mi * 16 + l15) * 136 + k0);
                acc[mi] = __builtin_amdgcn_mfma_f32_16x16x32_bf16(a, bfr, acc[mi], 0, 0, 0);
            }
        }
        int col = n0 + l15;
        float bias = b_cv[col];
        #pragma unroll
        for (int mi = 0; mi < 4; ++mi)
            #pragma unroll
            for (int r = 0; r < 4; ++r) {
                int row = mi * 16 + quad * 4 + r;
                outT[col * 68 + row] = acc[mi][r] + bias + xw[row * 132 + col];
            }
    }
    __syncthreads();

    // ---------- Phase 7: scatter outT[c][t] -> out (float4 along W) ----------
    #pragma unroll
    for (int j = 0; j < 4; ++j) {
        int i  = tid + j * 512;
        int c  = i >> 4;
        int td = (i >> 2) & 3;
        int th = i & 3;
        int t0 = td * 16 + th * 4;
        const float* op = outT + c * 68 + t0;
        float4 v = { op[0], op[1], op[2], op[3] };
        *(float4*)(out + base + (long)c * 262144 + td * 4096 + th * 64) = v;
    }
}

extern "C" void kernel_launch(void* const* d_in, const int* in_sizes, int n_in,
                              void* d_out, int out_size, void* d_ws, size_t ws_size,
                              hipStream_t stream) {
    (void)in_sizes; (void)n_in; (void)d_ws; (void)ws_size; (void)out_size;
    wattn_kernel<<<dim3(8192), dim3(512), SMEM_BYTES, stream>>>(
        (const float*)d_in[0], (const float*)d_in[1], (const float*)d_in[2],
        (const float*)d_in[3], (const float*)d_in[4], (const float*)d_in[5],
        (const float*)d_in[6], (const float*)d_in[7], (const float*)d_in[8],
        (float*)d_out);
}